// Round 11
// baseline (285.553 us; speedup 1.0000x reference)
//
#include <hip/hip_runtime.h>
#include <hip/hip_bf16.h>
#include <cstdint>
#include <cstddef>

typedef short bf16x8 __attribute__((ext_vector_type(8)));
typedef float f32x4 __attribute__((ext_vector_type(4)));

namespace {
constexpr int kB = 2048;
constexpr int kN = 65536;
constexpr int kF = 128;
constexpr int kLabels = 10;
constexpr int kIMax = 0x7fffffff;

constexpr int BCOLS = 128;          // cols per WG (owned for whole kernel)
constexpr int PROWS = 128;          // rows per panel
constexpr int NPANEL = kB / PROWS;  // 16 panels (all rows per WG)
constexpr int NCH = 4;              // K chunks of 32 (hi-only bf16 ranking)
constexpr int NSUB = kN / 16;       // 4096 bins of 16 strided cols
// hi-only bf16 ranking: sigma_d ~= 0.012; margin 0.25 ~= 20 sigma (needs >= 8).
// Rescore is exact fp32; margin only widens the rescored set slightly.
constexpr float kMargin = 0.25f;
}

#define TOP3_INSERT(dd, ii, D0, I0, D1, I1, D2, I2)                              \
  do {                                                                           \
    float _d = (dd); int _i = (ii);                                              \
    if (_d < (D0) || (_d == (D0) && _i < (I0))) {                                \
      (D2) = (D1); (I2) = (I1); (D1) = (D0); (I1) = (I0); (D0) = _d; (I0) = _i;  \
    } else if (_d < (D1) || (_d == (D1) && _i < (I1))) {                         \
      (D2) = (D1); (I2) = (I1); (D1) = _d; (I1) = _i;                            \
    } else if (_d < (D2) || (_d == (D2) && _i < (I2))) {                         \
      (D2) = _d; (I2) = _i;                                                      \
    }                                                                            \
  } while (0)

__device__ inline unsigned short f2bf(float a) {
  __hip_bfloat16 h = __float2bfloat16(a);
  return __builtin_bit_cast(unsigned short, h);
}

// ---------- kernel 1: fused pack (bf16 hi only) + sumsq (r9/r10 verbatim) ----
__global__ __launch_bounds__(256) void pack_sumsq_kernel(
    const float* __restrict__ x, const float* __restrict__ train,
    const float* __restrict__ features, unsigned short* __restrict__ Ap,
    unsigned short* __restrict__ Bp, float* __restrict__ left,
    float* __restrict__ right) {
  const int wid = (int)((blockIdx.x * 256 + threadIdx.x) >> 6);
  const int lane = threadIdx.x & 63;
  if (wid >= kB + kN) return;
  const float2 fv = reinterpret_cast<const float2*>(features)[lane];
  const float* src;
  unsigned short* dst;
  float pm0, pm1, sm0, sm1;
  if (wid < kB) {
    src = x + (size_t)wid * kF;
    dst = Ap + (size_t)wid * 128;
    pm0 = fv.x; pm1 = fv.y;   // pack f*x
    sm0 = 1.0f; sm1 = 1.0f;   // left = sum x^2
  } else {
    src = train + (size_t)(wid - kB) * kF;
    dst = Bp + (size_t)(wid - kB) * 128;
    pm0 = 1.0f; pm1 = 1.0f;   // pack raw w
    sm0 = fv.x; sm1 = fv.y;   // right = sum (f*w)^2
  }
  const float2 v = reinterpret_cast<const float2*>(src)[lane];
  const float pa = v.x * pm0, pb = v.y * pm1;
  const float sa = v.x * sm0, sb = v.y * sm1;
  const unsigned short ha = f2bf(pa), hb = f2bf(pb);
  reinterpret_cast<unsigned int*>(dst)[lane] = (unsigned int)ha | ((unsigned int)hb << 16);
  float s = sa * sa + sb * sb;
  #pragma unroll
  for (int m = 1; m <= 32; m <<= 1) s += __shfl_xor(s, m);
  if (lane == 0) {
    if (wid < kB) left[wid] = s;
    else right[wid - kB] = s;
  }
}

// ---------- kernel 2: barrier-free reg-resident-B KNN rank ----------
// grid 512 (one WG per 128-col slice, 2 WG/CU), 256 thr (4 waves: 2m x 2n).
// B slice (32 KB) loaded ONCE into 64 VGPRs (16 bf16x8 frags), reused for all
// 16 row-panels. A frags read directly from global per chunk (Ap = 512 KB,
// L2/L1-resident; lanes 0/16/32/48 share one 64B line -> full-line efficient).
// No LDS staging, no K-loop barriers: waves free-run at MFMA rate.
__global__ __launch_bounds__(256, 2) void knn_main_kernel(
    const unsigned short* __restrict__ Ap, const unsigned short* __restrict__ Bp,
    const float* __restrict__ left, const float* __restrict__ right,
    float* __restrict__ minbuf) {
  __shared__ float lsL[kB];  // 8 KB, staged once

  const int slice = blockIdx.x;
  const int col0 = slice * BCOLS;
  const int t = threadIdx.x;
  const int lane = t & 63;
  const int wm = (t >> 6) >> 1;  // 0..1
  const int wn = (t >> 6) & 1;   // 0..1

  #pragma unroll
  for (int i = 0; i < 2; ++i)
    reinterpret_cast<float4*>(lsL)[t + i * 256] =
        reinterpret_cast<const float4*>(left)[t + i * 256];
  __syncthreads();

  // right values for this lane's 4 col-fragments (WG-fixed cols)
  float rj[4];
  #pragma unroll
  for (int nf = 0; nf < 4; ++nf)
    rj[nf] = right[col0 + wn * 64 + nf * 16 + (lane & 15)];

  // B fragments: [c][nf], col = col0 + wn*64 + nf*16 + (lane&15),
  // k-bytes = c*64 + (lane>>4)*16. Row stride 256 B (128 bf16).
  const char* BpB = (const char*)Bp;
  bf16x8 bfr[4][4];
  #pragma unroll
  for (int c = 0; c < 4; ++c)
    #pragma unroll
    for (int nf = 0; nf < 4; ++nf) {
      const size_t addr =
          (size_t)(col0 + wn * 64 + nf * 16 + (lane & 15)) * 256 +
          (size_t)c * 64 + (size_t)(lane >> 4) * 16;
      bfr[c][nf] = *reinterpret_cast<const bf16x8*>(BpB + addr);
    }

  // A fragment base addresses (per mf), panel offset added in-loop.
  const char* ApB = (const char*)Ap;
  size_t abase[4];
  #pragma unroll
  for (int mf = 0; mf < 4; ++mf)
    abase[mf] = (size_t)(wm * 64 + mf * 16 + (lane & 15)) * 256 +
                (size_t)(lane >> 4) * 16;

  const bool bwriter = (lane & 3) == 0;
  const int subbase = slice * 8 + wn * 4 + ((lane >> 2) & 3);

  for (int mp = 0; mp < NPANEL; ++mp) {
    const size_t poff = (size_t)mp * (PROWS * 256);
    f32x4 acc[4][4];
    #pragma unroll
    for (int mf = 0; mf < 4; ++mf)
      #pragma unroll
      for (int nf = 0; nf < 4; ++nf)
        acc[mf][nf] = (f32x4){0.f, 0.f, 0.f, 0.f};

    #pragma unroll
    for (int c = 0; c < NCH; ++c) {
      bf16x8 a[4];
      #pragma unroll
      for (int mf = 0; mf < 4; ++mf)
        a[mf] = *reinterpret_cast<const bf16x8*>(
            ApB + abase[mf] + poff + (size_t)c * 64);
      __builtin_amdgcn_s_setprio(1);
      #pragma unroll
      for (int mf = 0; mf < 4; ++mf)
        #pragma unroll
        for (int nf = 0; nf < 4; ++nf)
          acc[mf][nf] = __builtin_amdgcn_mfma_f32_16x16x32_bf16(
              a[mf], bfr[c][nf], acc[mf][nf], 0, 0, 0);
      __builtin_amdgcn_s_setprio(0);
    }

    // panel epilogue: distance estimate + per-bin (16 strided cols) min.
    // bin = { wn*64 + nf*16 + bq*4 + g : nf 0..3, g 0..3 }, bq = (lane>>2)&3.
    const int prow0 = mp * PROWS + wm * 64;
    #pragma unroll
    for (int mf = 0; mf < 4; ++mf) {
      #pragma unroll
      for (int rg = 0; rg < 4; ++rg) {
        const int row = prow0 + mf * 16 + (lane >> 4) * 4 + rg;
        const float l = lsL[row];
        float d0 = sqrtf(l + rj[0]) - 2.0f * acc[mf][0][rg];
        float d1 = sqrtf(l + rj[1]) - 2.0f * acc[mf][1][rg];
        float d2 = sqrtf(l + rj[2]) - 2.0f * acc[mf][2][rg];
        float d3 = sqrtf(l + rj[3]) - 2.0f * acc[mf][3][rg];
        float v = fminf(fminf(d0, d1), fminf(d2, d3));
        v = fminf(v, __shfl_xor(v, 1));
        v = fminf(v, __shfl_xor(v, 2));
        if (bwriter)
          minbuf[(size_t)row * NSUB + subbase] = v;
      }
    }
  }
}

// ---------- kernel 3: select bins, exact fp32 rescore, outputs (r10 verbatim) -
__global__ __launch_bounds__(256) void select_rescore_kernel(
    const float* __restrict__ x, const float* __restrict__ train,
    const float* __restrict__ features, const float* __restrict__ left,
    const float* __restrict__ right, const int* __restrict__ labels,
    const float* __restrict__ minbuf, float* __restrict__ out) {
  __shared__ float Xs[4][kF];
  const int t = threadIdx.x;
  if (t < 128) {
    const int rr = t >> 5, q = t & 31;
    float4 xv = reinterpret_cast<const float4*>(
        x + (size_t)(blockIdx.x * 4 + rr) * kF)[q];
    const float4 f = reinterpret_cast<const float4*>(features)[q];
    xv.x *= f.x; xv.y *= f.y; xv.z *= f.z; xv.w *= f.w;
    reinterpret_cast<float4*>(&Xs[rr][0])[q] = xv;
  }
  __syncthreads();
  const int wave = t >> 6, lane = t & 63;
  const int row = blockIdx.x * 4 + wave;
  const float lr = left[row];
  const float* mrow = minbuf + (size_t)row * NSUB;

  // pass 1: 3rd-smallest bin min
  float v0 = __builtin_inff(), v1 = v0, v2 = v0;
  #pragma unroll 4
  for (int i = 0; i < NSUB / 64; ++i) {
    const float m = mrow[i * 64 + lane];
    if (m < v0) { v2 = v1; v1 = v0; v0 = m; }
    else if (m < v1) { v2 = v1; v1 = m; }
    else if (m < v2) { v2 = m; }
  }
  #pragma unroll
  for (int msk = 1; msk <= 32; msk <<= 1) {
    const float e0 = __shfl_xor(v0, msk), e1 = __shfl_xor(v1, msk), e2 = __shfl_xor(v2, msk);
    if (e0 < v0) { v2 = v1; v1 = v0; v0 = e0; } else if (e0 < v1) { v2 = v1; v1 = e0; } else if (e0 < v2) v2 = e0;
    if (e1 < v0) { v2 = v1; v1 = v0; v0 = e1; } else if (e1 < v1) { v2 = v1; v1 = e1; } else if (e1 < v2) v2 = e1;
    if (e2 < v0) { v2 = v1; v1 = v0; v0 = e2; } else if (e2 < v1) { v2 = v1; v1 = e2; } else if (e2 < v2) v2 = e2;
  }
  const float tau = v2 + kMargin;

  // pass 2: exact fp32 rescore of selected bins.
  // bin sub -> j = (sub>>3)*128 + ((sub>>2)&1)*64 + nf*16 + (sub&3)*4 + g,
  // nf = lane>>2 (0..3), g = lane&3, lanes 0..15 active.
  float d0 = __builtin_inff(), d1 = d0, d2 = d0;
  int i0 = kIMax, i1 = kIMax, i2 = kIMax;
  for (int base = 0; base < NSUB; base += 64) {
    const float m = mrow[base + lane];
    unsigned long long msk = __ballot(m <= tau);
    while (msk) {
      const int bpos = __builtin_ctzll(msk);
      msk &= msk - 1;
      const int sub = base + bpos;
      if (lane < 16) {
        const int j = (sub >> 3) * 128 + ((sub >> 2) & 1) * 64 +
                      (lane >> 2) * 16 + (sub & 3) * 4 + (lane & 3);
        const float4* wp = reinterpret_cast<const float4*>(train + (size_t)j * kF);
        float acc = 0.f;
        #pragma unroll 8
        for (int kq = 0; kq < 32; ++kq) {
          const float4 w4 = wp[kq];
          const float4 x4 = reinterpret_cast<const float4*>(&Xs[wave][0])[kq];
          acc = fmaf(x4.w, w4.w, fmaf(x4.z, w4.z, fmaf(x4.y, w4.y, fmaf(x4.x, w4.x, acc))));
        }
        const float d = sqrtf(lr + right[j]) - 2.0f * acc;
        TOP3_INSERT(d, j, d0, i0, d1, i1, d2, i2);
      }
    }
  }
  #pragma unroll
  for (int msk = 1; msk <= 32; msk <<= 1) {
    const float e0 = __shfl_xor(d0, msk), e1 = __shfl_xor(d1, msk), e2 = __shfl_xor(d2, msk);
    const int f0 = __shfl_xor(i0, msk), f1 = __shfl_xor(i1, msk), f2 = __shfl_xor(i2, msk);
    TOP3_INSERT(e0, f0, d0, i0, d1, i1, d2, i2);
    TOP3_INSERT(e1, f1, d0, i0, d1, i1, d2, i2);
    TOP3_INSERT(e2, f2, d0, i0, d1, i1, d2, i2);
  }
  if (lane == 0) {
    const int l0 = labels[i0], l1 = labels[i1], l2 = labels[i2];
    const int o = (l0 + l1 + l2) / 3;
    float* one_hot = out;
    float* values = out + (size_t)kB * kLabels;
    float* indices = values + (size_t)kB * 3;
    float* labs = indices + (size_t)kB * 3;
    #pragma unroll
    for (int c = 0; c < kLabels; ++c)
      one_hot[(size_t)row * kLabels + c] = (c == o) ? 1.0f : 0.0f;
    values[row * 3 + 0] = -d0; values[row * 3 + 1] = -d1; values[row * 3 + 2] = -d2;
    indices[row * 3 + 0] = (float)i0; indices[row * 3 + 1] = (float)i1; indices[row * 3 + 2] = (float)i2;
    labs[row * 3 + 0] = (float)l0; labs[row * 3 + 1] = (float)l1; labs[row * 3 + 2] = (float)l2;
  }
}

extern "C" void kernel_launch(void* const* d_in, const int* in_sizes, int n_in,
                              void* d_out, int out_size, void* d_ws, size_t ws_size,
                              hipStream_t stream) {
  const float* x = (const float*)d_in[0];
  const float* train = (const float*)d_in[1];
  const int* labels = (const int*)d_in[2];
  const float* features = (const float*)d_in[3];
  float* out = (float*)d_out;

  char* ws = (char*)d_ws;
  unsigned short* Bp = (unsigned short*)ws;                       // 16 MB (hi)
  unsigned short* Ap = (unsigned short*)(ws + 16777216);          // 512 KB (hi)
  float* left = (float*)(ws + 17301504);                          // 8 KB
  float* right = (float*)(ws + 17309696);                         // 256 KB
  float* minbuf = (float*)(ws + 17571840);                        // 32 MB

  pack_sumsq_kernel<<<((kB + kN) * 64 + 255) / 256, 256, 0, stream>>>(
      x, train, features, Ap, Bp, left, right);
  knn_main_kernel<<<kN / BCOLS, 256, 0, stream>>>(Ap, Bp, left, right, minbuf);
  select_rescore_kernel<<<kB / 4, 256, 0, stream>>>(
      x, train, features, left, right, labels, minbuf, out);
}